// Round 2
// baseline (1426.198 us; speedup 1.0000x reference)
//
#include <hip/hip_runtime.h>
#include <hip/hip_bf16.h>

typedef __attribute__((ext_vector_type(8))) short short8;
typedef __attribute__((ext_vector_type(4))) float floatx4;

using bf16 = __hip_bfloat16;

__device__ __forceinline__ void cp16_g2l(bf16* lds, const bf16* g) {
  __builtin_amdgcn_global_load_lds(
      (const __attribute__((address_space(1))) unsigned int*)g,
      (__attribute__((address_space(3))) unsigned int*)lds,
      16, 0, 0);
}

__device__ __forceinline__ float gelu_exact(float x) {
  return 0.5f * x * (1.0f + erff(x * 0.70710678118654752f));
}

// ---------------------------------------------------------------------------
// 256x256 tile GEMM, BK=64, 8 waves (2Mx4N), bf16 MFMA 16x16x32, fp32 accum.
// C[M,N] = A[M,K] @ Bt[N,K]^T, batched via blockIdx.z.
// LDS: 2 double-buffered K-tiles (A 256x64 + B 256x64 each) = 128 KiB.
// Swizzle: 16B slot u at row r lives at physical slot u^(r&7)  (T2, rule #21:
// linear gload_lds dest + inverse-swizzled global source + swizzled ds_read).
// Schedule: counted vmcnt(8) (T4) with raw s_barrier; stage tile t+2 into the
// slot freed by compute of tile t; vmcnt(8)+barrier then guarantees tile t+1
// landed for all waves while tile t+2's 8 loads stay in flight.
// MODE 0: out bf16 = acc + bias
// MODE 1: out f32  = acc * scale
// MODE 2: out bf16 = acc
// MODE 3: out f32  = acc + bias + resid   (resid may alias out)
// MODE 4: out bf16 = gelu(acc + bias)
// ---------------------------------------------------------------------------
template<int MODE>
__global__ __launch_bounds__(512)
void gemm256(const bf16* __restrict__ A, long sAb, long lda,
             const bf16* __restrict__ Bt, long sBb, long ldb,
             const float* __restrict__ bias,
             const float* __restrict__ resid,
             void* __restrict__ out, long sOb,
             int N, int K, float scale)
{
  __shared__ __attribute__((aligned(16))) bf16 sA[2 * 16384];  // [2][256][64]
  __shared__ __attribute__((aligned(16))) bf16 sB[2 * 16384];

  const int tid = threadIdx.x;
  const int l = tid & 63, w = tid >> 6;
  const int bz = blockIdx.z;
  const long row0 = (long)blockIdx.x * 256;
  const long col0 = (long)blockIdx.y * 256;
  const bf16* Ab = A + (long)bz * sAb + row0 * lda;
  const bf16* Bb = Bt + (long)bz * sBb + col0 * ldb;

  const int wr = w >> 2, wc = w & 3;          // wave tile: rows wr*128, cols wc*64
  const int g = l >> 4, t = l & 15;

  floatx4 acc[8][4];
  #pragma unroll
  for (int i = 0; i < 8; ++i)
    #pragma unroll
    for (int j = 0; j < 4; ++j)
      acc[i][j] = (floatx4){0.f, 0.f, 0.f, 0.f};

  // ---- staging: 4+4 gload_lds per thread per K-tile -----------------------
  auto stage = [&](int kt, int slot) {
    const long kb = (long)kt * 64;
    #pragma unroll
    for (int j = 0; j < 4; ++j) {
      const int L = tid + j * 512;            // linear 16B slot (lane-ordered)
      const int r = L >> 3, u = L & 7;
      const int cs = u ^ (r & 7);             // inverse-swizzled source slot
      cp16_g2l(sA + slot * 16384 + L * 8, Ab + (long)r * lda + kb + cs * 8);
    }
    #pragma unroll
    for (int j = 0; j < 4; ++j) {
      const int L = tid + j * 512;
      const int r = L >> 3, u = L & 7;
      const int cs = u ^ (r & 7);
      cp16_g2l(sB + slot * 16384 + L * 8, Bb + (long)r * ldb + kb + cs * 8);
    }
  };

  // ---- swizzled fragment read ---------------------------------------------
  auto rd = [&](const bf16* tile, int row, int u0) -> short8 {
    return *(const short8*)(tile + row * 64 + ((u0 ^ (row & 7)) << 3));
  };

  // ---- one K-tile of MFMA (64 per wave), quadrant-phased ------------------
  auto compute = [&](int slot) {
    const bf16* tA = sA + slot * 16384;
    const bf16* tB = sB + slot * 16384;
    #pragma unroll
    for (int qm = 0; qm < 2; ++qm) {
      short8 a[4][2];
      #pragma unroll
      for (int mi = 0; mi < 4; ++mi)
        #pragma unroll
        for (int ks = 0; ks < 2; ++ks)
          a[mi][ks] = rd(tA, wr * 128 + qm * 64 + mi * 16 + t, ks * 4 + g);
      #pragma unroll
      for (int qn = 0; qn < 2; ++qn) {
        short8 b[2][2];
        #pragma unroll
        for (int ni = 0; ni < 2; ++ni)
          #pragma unroll
          for (int ks = 0; ks < 2; ++ks)
            b[ni][ks] = rd(tB, wc * 64 + qn * 32 + ni * 16 + t, ks * 4 + g);
        __builtin_amdgcn_s_setprio(1);
        #pragma unroll
        for (int mi = 0; mi < 4; ++mi)
          #pragma unroll
          for (int ni = 0; ni < 2; ++ni)
            #pragma unroll
            for (int ks = 0; ks < 2; ++ks)
              acc[qm * 4 + mi][qn * 2 + ni] = __builtin_amdgcn_mfma_f32_16x16x32_bf16(
                  a[mi][ks], b[ni][ks], acc[qm * 4 + mi][qn * 2 + ni], 0, 0, 0);
        __builtin_amdgcn_s_setprio(0);
      }
    }
  };

  const int nt = K >> 6;  // K multiple of 64, nt >= 2 for all our shapes

  // prologue: tiles 0,1 into slots 0,1; wait tile 0 (tile 1's 8 stay in flight)
  stage(0, 0);
  stage(1, 1);
  asm volatile("s_waitcnt vmcnt(8)" ::: "memory");
  __builtin_amdgcn_s_barrier();
  __builtin_amdgcn_sched_barrier(0);

  for (int kt = 0; kt < nt; ++kt) {
    const int slot = kt & 1;
    compute(slot);
    __builtin_amdgcn_sched_barrier(0);
    __builtin_amdgcn_s_barrier();            // all waves done reading `slot`
    __builtin_amdgcn_sched_barrier(0);
    if (kt + 2 < nt) {
      stage(kt + 2, slot);                   // refill freed slot
      asm volatile("s_waitcnt vmcnt(8)" ::: "memory");  // tile kt+1 landed
      __builtin_amdgcn_s_barrier();
      __builtin_amdgcn_sched_barrier(0);
    } else if (kt + 1 < nt) {
      asm volatile("s_waitcnt vmcnt(0)" ::: "memory");  // tail: drain tile kt+1
      __builtin_amdgcn_s_barrier();
      __builtin_amdgcn_sched_barrier(0);
    }
  }

  // ---- epilogue: C/D layout col = lane&15, row = (lane>>4)*4 + r [m89] ----
  const long orow0 = row0 + wr * 128 + g * 4;
  const long ocol0 = col0 + wc * 64 + t;

  if constexpr (MODE == 0 || MODE == 2 || MODE == 4) {
    bf16* O = (bf16*)out + (long)bz * sOb;
    #pragma unroll
    for (int ni = 0; ni < 4; ++ni) {
      const long cc = ocol0 + ni * 16;
      float bv = 0.f;
      if constexpr (MODE != 2) bv = bias[cc];
      #pragma unroll
      for (int mi = 0; mi < 8; ++mi) {
        #pragma unroll
        for (int r = 0; r < 4; ++r) {
          float vv = acc[mi][ni][r] + bv;
          if constexpr (MODE == 4) vv = gelu_exact(vv);
          O[(orow0 + mi * 16 + r) * (long)N + cc] = __float2bfloat16(vv);
        }
      }
    }
  } else if constexpr (MODE == 1) {
    float* O = (float*)out + (long)bz * sOb;
    #pragma unroll
    for (int ni = 0; ni < 4; ++ni) {
      const long cc = ocol0 + ni * 16;
      #pragma unroll
      for (int mi = 0; mi < 8; ++mi)
        #pragma unroll
        for (int r = 0; r < 4; ++r)
          O[(orow0 + mi * 16 + r) * (long)N + cc] = acc[mi][ni][r] * scale;
    }
  } else {  // MODE 3
    float* O = (float*)out;
    #pragma unroll
    for (int ni = 0; ni < 4; ++ni) {
      const long cc = ocol0 + ni * 16;
      const float bv = bias[cc];
      #pragma unroll
      for (int mi = 0; mi < 8; ++mi) {
        #pragma unroll
        for (int r = 0; r < 4; ++r) {
          const long idx = (orow0 + mi * 16 + r) * (long)N + cc;
          O[idx] = acc[mi][ni][r] + bv + resid[idx];
        }
      }
    }
  }
}

// row LayerNorm over D=768, fp32 in -> bf16 out
__global__ __launch_bounds__(256)
void ln_kernel(const float* __restrict__ X, const float* __restrict__ G,
               const float* __restrict__ Bv, bf16* __restrict__ H)
{
  const int tid = threadIdx.x;
  const long row = blockIdx.x;
  const float* xr = X + row * 768;
  const float v0 = xr[tid], v1 = xr[tid + 256], v2 = xr[tid + 512];
  float s = v0 + v1 + v2;
  float s2 = v0 * v0 + v1 * v1 + v2 * v2;
  #pragma unroll
  for (int o = 32; o > 0; o >>= 1) {
    s += __shfl_xor(s, o);
    s2 += __shfl_xor(s2, o);
  }
  __shared__ float red[8];
  const int w = tid >> 6, l = tid & 63;
  if (l == 0) { red[w] = s; red[w + 4] = s2; }
  __syncthreads();
  s = red[0] + red[1] + red[2] + red[3];
  s2 = red[4] + red[5] + red[6] + red[7];
  const float mu = s * (1.f / 768.f);
  const float var = s2 * (1.f / 768.f) - mu * mu;
  const float rstd = rsqrtf(var + 1e-5f);
  bf16* hr = H + row * 768;
  hr[tid]       = __float2bfloat16((v0 - mu) * rstd * G[tid]       + Bv[tid]);
  hr[tid + 256] = __float2bfloat16((v1 - mu) * rstd * G[tid + 256] + Bv[tid + 256]);
  hr[tid + 512] = __float2bfloat16((v2 - mu) * rstd * G[tid + 512] + Bv[tid + 512]);
}

// row softmax over 2048 keys, fp32 scores -> bf16 probs
__global__ __launch_bounds__(256)
void softmax_kernel(const float* __restrict__ S, bf16* __restrict__ P)
{
  const int tid = threadIdx.x;
  const long row = blockIdx.x;
  const float* sr = S + row * 2048;
  float v[8];
  float mx = -1e30f;
  #pragma unroll
  for (int j = 0; j < 8; ++j) { v[j] = sr[tid + 256 * j]; mx = fmaxf(mx, v[j]); }
  #pragma unroll
  for (int o = 32; o > 0; o >>= 1) mx = fmaxf(mx, __shfl_xor(mx, o));
  __shared__ float red[4];
  const int w = tid >> 6, l = tid & 63;
  if (l == 0) red[w] = mx;
  __syncthreads();
  mx = fmaxf(fmaxf(red[0], red[1]), fmaxf(red[2], red[3]));
  float sum = 0.f;
  #pragma unroll
  for (int j = 0; j < 8; ++j) { v[j] = __expf(v[j] - mx); sum += v[j]; }
  #pragma unroll
  for (int o = 32; o > 0; o >>= 1) sum += __shfl_xor(sum, o);
  __syncthreads();
  if (l == 0) red[w] = sum;
  __syncthreads();
  sum = red[0] + red[1] + red[2] + red[3];
  const float inv = 1.f / sum;
  bf16* pr = P + row * 2048;
  #pragma unroll
  for (int j = 0; j < 8; ++j) pr[tid + 256 * j] = __float2bfloat16(v[j] * inv);
}

// Wt[n][k] = bf16(W[k][n]) ; W fp32 [K][N]. block (32,8)
__global__ void transpose_w(const float* __restrict__ W, bf16* __restrict__ Wt,
                            int K, int N)
{
  __shared__ float tile[32][33];
  const int n0 = blockIdx.x * 32, k0 = blockIdx.y * 32;
  const int tx = threadIdx.x, ty = threadIdx.y;
  #pragma unroll
  for (int j = ty; j < 32; j += 8)
    tile[j][tx] = W[(long)(k0 + j) * N + n0 + tx];
  __syncthreads();
  #pragma unroll
  for (int j = ty; j < 32; j += 8)
    Wt[(long)(n0 + j) * K + k0 + tx] = __float2bfloat16(tile[tx][j]);
}

// Vt[b][d][s] = qkv[(b*2048+s)*2304 + 1536 + d]  (bf16 v-slice of fused qkv)
__global__ void transpose_v(const bf16* __restrict__ QKV, bf16* __restrict__ Vt)
{
  __shared__ bf16 tile[32][33];
  const int d0 = blockIdx.x * 32, s0 = blockIdx.y * 32, b = blockIdx.z;
  const int tx = threadIdx.x, ty = threadIdx.y;
  #pragma unroll
  for (int j = ty; j < 32; j += 8)
    tile[j][tx] = QKV[((long)b * 2048 + s0 + j) * 2304 + 1536 + d0 + tx];
  __syncthreads();
  #pragma unroll
  for (int j = ty; j < 32; j += 8)
    Vt[(long)b * 768 * 2048 + (long)(d0 + j) * 2048 + s0 + tx] = tile[tx][j];
}

// concat 3x768 fp32 biases
__global__ void concat3(const float* __restrict__ a, const float* __restrict__ b,
                        const float* __restrict__ c, float* __restrict__ o)
{
  const int i = threadIdx.x + blockIdx.x * 256;
  if (i < 768) { o[i] = a[i]; o[i + 768] = b[i]; o[i + 1536] = c[i]; }
}

extern "C" void kernel_launch(void* const* d_in, const int* in_sizes, int n_in,
                              void* d_out, int out_size, void* d_ws, size_t ws_size,
                              hipStream_t stream)
{
  const float* x     = (const float*)d_in[0];
  const float* ln1g  = (const float*)d_in[1];
  const float* ln1b  = (const float*)d_in[2];
  const float* ln2g  = (const float*)d_in[3];
  const float* ln2b  = (const float*)d_in[4];
  const float* Wq    = (const float*)d_in[5];
  const float* bq    = (const float*)d_in[6];
  const float* Wk    = (const float*)d_in[7];
  const float* bk    = (const float*)d_in[8];
  const float* Wv    = (const float*)d_in[9];
  const float* bvv   = (const float*)d_in[10];
  const float* Wo    = (const float*)d_in[11];
  const float* bo    = (const float*)d_in[12];
  const float* Wfc   = (const float*)d_in[13];
  const float* bfc   = (const float*)d_in[14];
  const float* Wproj = (const float*)d_in[15];
  const float* bproj = (const float*)d_in[16];
  float* out = (float*)d_out;

  constexpr int Bz = 8, S = 2048, D = 768, Hh = 3072, QKVN = 3 * D;
  constexpr long Mtot = (long)Bz * S;  // 16384

  char* ws = (char*)d_ws;
  size_t off = 0;
  auto alloc = [&](size_t bytes) -> char* {
    char* p = ws + off;
    off += (bytes + 255) & ~(size_t)255;
    return p;
  };
  bf16* wqkvT = (bf16*)alloc((size_t)QKVN * D * 2);
  bf16* woT   = (bf16*)alloc((size_t)D * D * 2);
  bf16* wfcT  = (bf16*)alloc((size_t)Hh * D * 2);
  bf16* wprT  = (bf16*)alloc((size_t)D * Hh * 2);
  float* bqkv = (float*)alloc((size_t)QKVN * 4);
  bf16* hb    = (bf16*)alloc((size_t)Mtot * D * 2);
  bf16* qkv   = (bf16*)alloc((size_t)Mtot * QKVN * 2);
  bf16* vtb   = (bf16*)alloc((size_t)Mtot * D * 2);
  bf16* yb    = (bf16*)alloc((size_t)Mtot * D * 2);

  int nbat = Bz;
  size_t region = (size_t)nbat * S * S * 6;              // scores f32 + attn bf16
  const size_t mbytes = (size_t)Mtot * Hh * 2;           // MLP hidden bf16
  if (region < mbytes) region = mbytes;
  if (off + region > ws_size) {                          // fallback: per-batch attention
    nbat = 1;
    region = mbytes;
  }
  char* reg = alloc(region);
  float* scores = (float*)reg;
  bf16* attn = (bf16*)(reg + (size_t)nbat * S * S * 4);
  bf16* mb = (bf16*)reg;  // aliases scores/attn (used after attention done)

  const dim3 tb(32, 8);

  // weight prep (bf16, [N][K]); q/k/v stacked into wqkvT rows 0/768/1536
  transpose_w<<<dim3(D / 32, D / 32), tb, 0, stream>>>(Wq, wqkvT, D, D);
  transpose_w<<<dim3(D / 32, D / 32), tb, 0, stream>>>(Wk, wqkvT + (size_t)D * D, D, D);
  transpose_w<<<dim3(D / 32, D / 32), tb, 0, stream>>>(Wv, wqkvT + 2 * (size_t)D * D, D, D);
  transpose_w<<<dim3(D / 32, D / 32), tb, 0, stream>>>(Wo, woT, D, D);
  transpose_w<<<dim3(Hh / 32, D / 32), tb, 0, stream>>>(Wfc, wfcT, D, Hh);
  transpose_w<<<dim3(D / 32, Hh / 32), tb, 0, stream>>>(Wproj, wprT, Hh, D);
  concat3<<<3, 256, 0, stream>>>(bq, bk, bvv, bqkv);

  // LN1 -> h (bf16)
  ln_kernel<<<(int)Mtot, 256, 0, stream>>>(x, ln1g, ln1b, hb);

  // fused QKV projection: [16384,768] @ [2304,768]^T -> [16384,2304]
  gemm256<0><<<dim3(Mtot / 256, QKVN / 256, 1), 512, 0, stream>>>(
      hb, 0, D, wqkvT, 0, D, bqkv, nullptr, qkv, 0, QKVN, D, 1.f);
  transpose_v<<<dim3(D / 32, S / 32, Bz), tb, 0, stream>>>(qkv, vtb);

  // attention: scores -> softmax -> PV, grouped by nbat batches
  const float sc = 0.03608439182435161f;  // 1/sqrt(768)
  for (int g0 = 0; g0 < Bz; g0 += nbat) {
    const bf16* qg  = qkv + (long)g0 * S * QKVN;          // q slice, lda=2304
    const bf16* kg  = qkv + (long)g0 * S * QKVN + D;      // k slice, ldb=2304
    const bf16* vtg = vtb + (long)g0 * D * S;
    bf16* yg = yb + (long)g0 * S * D;
    gemm256<1><<<dim3(S / 256, S / 256, nbat), 512, 0, stream>>>(
        qg, (long)S * QKVN, QKVN, kg, (long)S * QKVN, QKVN, nullptr, nullptr,
        scores, (long)S * S, S, D, sc);
    softmax_kernel<<<nbat * S, 256, 0, stream>>>(scores, attn);
    gemm256<2><<<dim3(S / 256, D / 256, nbat), 512, 0, stream>>>(
        attn, (long)S * S, S, vtg, (long)D * S, S, nullptr, nullptr,
        yg, (long)S * D, D, S, 1.f);
  }

  // out-projection + residual -> d_out (fp32)
  gemm256<3><<<dim3(Mtot / 256, D / 256, 1), 512, 0, stream>>>(
      yb, 0, D, woT, 0, D, bo, x, out, 0, D, D, 1.f);

  // LN2 -> h2 (bf16, reuse hb)
  ln_kernel<<<(int)Mtot, 256, 0, stream>>>(out, ln2g, ln2b, hb);

  // MLP: fc + exact GELU -> mb (bf16), then proj + residual (in-place on d_out)
  gemm256<4><<<dim3(Mtot / 256, Hh / 256, 1), 512, 0, stream>>>(
      hb, 0, D, wfcT, 0, D, bfc, nullptr, mb, 0, Hh, D, 1.f);
  gemm256<3><<<dim3(Mtot / 256, D / 256, 1), 512, 0, stream>>>(
      mb, 0, Hh, wprT, 0, Hh, bproj, out, out, 0, D, Hh, 1.f);
}